// Round 4
// baseline (455.398 us; speedup 1.0000x reference)
//
#include <hip/hip_runtime.h>

typedef float  f32x4  __attribute__((ext_vector_type(4)));
typedef __bf16 bf16x8 __attribute__((ext_vector_type(8)));
typedef __bf16 bf16x4 __attribute__((ext_vector_type(4)));

#define L2EPS   1e-12f
#define SHRINKC 0.0025f

// ---- helpers -------------------------------------------------------------

__device__ __forceinline__ bf16x8 pack_bf16(f32x4 v0, f32x4 v1) {
  bf16x8 r;
  r[0] = (__bf16)v0[0]; r[1] = (__bf16)v0[1]; r[2] = (__bf16)v0[2]; r[3] = (__bf16)v0[3];
  r[4] = (__bf16)v1[0]; r[5] = (__bf16)v1[1]; r[6] = (__bf16)v1[2]; r[7] = (__bf16)v1[3];
  return r;
}

__device__ __forceinline__ bf16x8 load_cvt_bf16x8(const float* p) {
  const f32x4* q = (const f32x4*)p;
  return pack_bf16(q[0], q[1]);
}

__device__ __forceinline__ float dot4(f32x4 v) {
  return v[0]*v[0] + v[1]*v[1] + v[2]*v[2] + v[3]*v[3];
}

// ---- gemm1: h = relu(memory @ w1^T + b1), 32x32 tile / 1-wave block ------
// grid = (16,16), block = 64. Also zeroes attsum (64 floats per block).
__global__ __launch_bounds__(64) void gemm1(
    const float* __restrict__ A, const float* __restrict__ B,
    const float* __restrict__ bias, float* __restrict__ C,
    float* __restrict__ attsum) {
  const int bid = blockIdx.y * gridDim.x + blockIdx.x;  // 0..255
  attsum[bid * 64 + threadIdx.x] = 0.f;

  const int K = 1024, N = 512;
  const int r0   = blockIdx.x * 32;
  const int n0   = blockIdx.y * 32;
  const int lane = threadIdx.x & 63;
  const int quad = lane >> 4;
  const int m    = lane & 15;

  f32x4 acc[2][2] = {};
  for (int k0 = 0; k0 < K; k0 += 32) {
    const int kk = k0 + quad * 8;
    bf16x8 a[2], b[2];
    #pragma unroll
    for (int rg = 0; rg < 2; ++rg)
      a[rg] = load_cvt_bf16x8(A + (size_t)(r0 + rg * 16 + m) * K + kk);
    #pragma unroll
    for (int cf = 0; cf < 2; ++cf)
      b[cf] = load_cvt_bf16x8(B + (size_t)(n0 + cf * 16 + m) * K + kk);
    #pragma unroll
    for (int rg = 0; rg < 2; ++rg)
      #pragma unroll
      for (int cf = 0; cf < 2; ++cf)
        acc[rg][cf] = __builtin_amdgcn_mfma_f32_16x16x32_bf16(a[rg], b[cf], acc[rg][cf], 0, 0, 0);
  }
  #pragma unroll
  for (int rg = 0; rg < 2; ++rg)
    #pragma unroll
    for (int cf = 0; cf < 2; ++cf) {
      const int n = n0 + cf * 16 + m;
      const float bv = bias[n];
      #pragma unroll
      for (int vi = 0; vi < 4; ++vi) {
        const int r = r0 + rg * 16 + quad * 4 + vi;
        C[(size_t)r * N + n] = fmaxf(acc[rg][cf][vi] + bv, 0.f);
      }
    }
}

// ---- gemm2: mp = relu(h @ w2^T + b2), 32x32 tile / 1-wave block ----------
// grid = (16, 32), block = 64. 512 blocks: 2 blocks/CU, latency hidden.
// (Round-2 lesson: a 16-block fused variant ran at 150 us, 0.7% occupancy.)
__global__ __launch_bounds__(64) void gemm2(
    const float* __restrict__ A, const float* __restrict__ B,
    const float* __restrict__ bias, float* __restrict__ C) {
  const int K = 512, N = 1024;
  const int r0   = blockIdx.x * 32;
  const int n0   = blockIdx.y * 32;
  const int lane = threadIdx.x & 63;
  const int quad = lane >> 4;
  const int m    = lane & 15;

  f32x4 acc[2][2] = {};
  for (int k0 = 0; k0 < K; k0 += 32) {
    const int kk = k0 + quad * 8;
    bf16x8 a[2], b[2];
    #pragma unroll
    for (int rg = 0; rg < 2; ++rg)
      a[rg] = load_cvt_bf16x8(A + (size_t)(r0 + rg * 16 + m) * K + kk);
    #pragma unroll
    for (int cf = 0; cf < 2; ++cf)
      b[cf] = load_cvt_bf16x8(B + (size_t)(n0 + cf * 16 + m) * K + kk);
    #pragma unroll
    for (int rg = 0; rg < 2; ++rg)
      #pragma unroll
      for (int cf = 0; cf < 2; ++cf)
        acc[rg][cf] = __builtin_amdgcn_mfma_f32_16x16x32_bf16(a[rg], b[cf], acc[rg][cf], 0, 0, 0);
  }
  #pragma unroll
  for (int rg = 0; rg < 2; ++rg)
    #pragma unroll
    for (int cf = 0; cf < 2; ++cf) {
      const int n = n0 + cf * 16 + m;
      const float bv = bias[n];
      #pragma unroll
      for (int vi = 0; vi < 4; ++vi) {
        const int r = r0 + rg * 16 + quad * 4 + vi;
        C[(size_t)r * N + n] = fmaxf(acc[rg][cf][vi] + bv, 0.f);
      }
    }
}

// ---- normalize mem_proc rows -> memory_norm (fp32 out + bf16 ws copy) ----
// grid = 512, block = 256
__global__ __launch_bounds__(256) void norm_rows(
    const float* __restrict__ mp, float* __restrict__ mn_f32,
    __bf16* __restrict__ mn_bf16) {
  const int r = blockIdx.x;
  const int tid = threadIdx.x;
  const f32x4 v = *(const f32x4*)(mp + (size_t)r * 1024 + tid * 4);
  float ss = dot4(v);
  #pragma unroll
  for (int d = 1; d < 64; d <<= 1) ss += __shfl_xor(ss, d);
  __shared__ float wsum[4];
  __shared__ float invs;
  if ((tid & 63) == 0) wsum[tid >> 6] = ss;
  __syncthreads();
  if (tid == 0) {
    float t = wsum[0] + wsum[1] + wsum[2] + wsum[3];
    invs = 1.f / fmaxf(sqrtf(t), L2EPS);
  }
  __syncthreads();
  const float iv = invs;
  f32x4 o = v * iv;
  *(f32x4*)(mn_f32 + (size_t)r * 1024 + tid * 4) = o;
  bf16x4 ob;
  ob[0] = (__bf16)o[0]; ob[1] = (__bf16)o[1]; ob[2] = (__bf16)o[2]; ob[3] = (__bf16)o[3];
  *(bf16x4*)(mn_bf16 + (size_t)r * 1024 + tid * 4) = ob;
}

// ---- fused attention, register-resident softmax, 16 rows/block -----------
// Swapped MFMA operands: mfma(A=Mn rows, B=x rows) puts, in each lane,
// 32 score values (8 nf-tiles x 4 vi) belonging to ONE x-row:
//   row = r0 + (lane&15), col = n0w + nf*16 + (lane>>4)*4 + vi
// Softmax is in-register: shfl_xor(16|32) over quads + 256 B LDS cross-wave.
// grid = 1024 (16 rows each), block = 256 (4 waves; wave w owns cols w*128..)
// vs round-3: half the rows/block -> acc 64->32 VGPRs, blocks/CU 2->4,
// waves/CU 8->16 (latency hiding was the limiter; traffic unchanged).
// flat-copy of x is distributed: wave w writes k-range [256w, 256w+256).
__global__ __launch_bounds__(256) void attend(
    const float* __restrict__ x, const __bf16* __restrict__ Mn,
    const float* __restrict__ Mnf, float* __restrict__ out_flat,
    float* __restrict__ out_out, float* __restrict__ out_att,
    float* __restrict__ attsum) {
  __shared__ float red[2][4][16];  // [phase][wave][row] partial sums
  const int r0   = blockIdx.x * 16;
  const int tid  = threadIdx.x;
  const int wave = tid >> 6;
  const int lane = tid & 63;
  const int quad = lane >> 4;
  const int m    = lane & 15;
  const int n0w  = wave * 128;

  float ss0 = 0.f;
  f32x4 acc[8] = {};
  for (int k0 = 0; k0 < 1024; k0 += 32) {
    const int kk = k0 + quad * 8;
    bf16x8 b0;
    f32x4 v0a, v0b;
    {
      const f32x4* q = (const f32x4*)(x + (size_t)(r0 + m) * 1024 + kk);
      v0a = q[0]; v0b = q[1];
      b0 = pack_bf16(v0a, v0b);
      ss0 += dot4(v0a) + dot4(v0b);
    }
    if ((k0 >> 8) == wave) {
      // exact fp32 copy of x -> input_flat, spread over the 4 waves
      float* d0 = out_flat + (size_t)(r0 + m) * 1024 + kk;
      __builtin_nontemporal_store(v0a, (f32x4*)d0);
      __builtin_nontemporal_store(v0b, (f32x4*)(d0 + 4));
    }
    #pragma unroll
    for (int nf = 0; nf < 8; ++nf) {
      const bf16x8 a = *(const bf16x8*)(Mn + (size_t)(n0w + nf * 16 + m) * 1024 + kk);
      acc[nf] = __builtin_amdgcn_mfma_f32_16x16x32_bf16(a, b0, acc[nf], 0, 0, 0);
    }
  }
  // row sumsq: reduce across quads (lanes share m) -> every lane has its row
  ss0 += __shfl_xor(ss0, 16); ss0 += __shfl_xor(ss0, 32);
  const float iv0 = 1.f / fmaxf(sqrtf(ss0), L2EPS);

  // exp in place (no max-shift: scores are cosines in [-1,1]), per-row sums
  float se0 = 0.f;
  #pragma unroll
  for (int nf = 0; nf < 8; ++nf)
    #pragma unroll
    for (int vi = 0; vi < 4; ++vi) {
      const float e0 = __expf(acc[nf][vi] * iv0);
      acc[nf][vi] = e0;
      se0 += e0;
    }
  se0 += __shfl_xor(se0, 16); se0 += __shfl_xor(se0, 32);
  if (quad == 0) red[0][wave][m] = se0;
  __syncthreads();
  const float te0 = red[0][0][m] + red[0][1][m] + red[0][2][m] + red[0][3][m];
  const float ie0 = 1.f / te0;

  // shrink in place, accumulate row sums of surviving mass
  float rs0 = 0.f;
  #pragma unroll
  for (int nf = 0; nf < 8; ++nf)
    #pragma unroll
    for (int vi = 0; vi < 4; ++vi) {
      const float s0 = fmaxf(acc[nf][vi] * ie0 - SHRINKC, 0.f);
      acc[nf][vi] = s0;
      rs0 += s0;
    }
  rs0 += __shfl_xor(rs0, 16); rs0 += __shfl_xor(rs0, 32);
  if (quad == 0) red[1][wave][m] = rs0;
  __syncthreads();
  const float tr0 = red[1][0][m] + red[1][1][m] + red[1][2][m] + red[1][3][m];
  const float ir0 = 1.f / fmaxf(tr0, L2EPS);

  // final att values straight from registers (f32x4, line-coalesced)
  #pragma unroll
  for (int nf = 0; nf < 8; ++nf) {
    acc[nf] *= ir0;
    __builtin_nontemporal_store(acc[nf],
        (f32x4*)(out_att + (size_t)(r0 + m) * 512 + n0w + nf * 16 + quad * 4));
  }
  __threadfence_block();
  const int any = __syncthreads_or(tr0 > 0.f);

  if (!any) {
    // fast path (data-driven): all rows shrunk to zero -> output rows are 0,
    // attsum contribution is 0. Pure streaming store.
    const f32x4 z = {0.f, 0.f, 0.f, 0.f};
    float* dst = out_out + (size_t)r0 * 1024;
    for (int idx = tid; idx < 16 * 1024 / 4; idx += 256)
      __builtin_nontemporal_store(z, (f32x4*)(dst + idx * 4));
  } else {
    // general path (correctness-only; not taken on this data distribution)
    const int nimg = r0 >> 9;
    #pragma unroll
    for (int nf = 0; nf < 8; ++nf) {
      f32x4 v = acc[nf];  // this lane's row; sum over the 16 rows (lanes m)
      #pragma unroll
      for (int d = 1; d < 16; d <<= 1) {
        v[0] += __shfl_xor(v[0], d); v[1] += __shfl_xor(v[1], d);
        v[2] += __shfl_xor(v[2], d); v[3] += __shfl_xor(v[3], d);
      }
      if (m == 0) {
        const int c = n0w + nf * 16 + quad * 4;
        atomicAdd(&attsum[nimg * 512 + c + 0], v[0]);
        atomicAdd(&attsum[nimg * 512 + c + 1], v[1]);
        atomicAdd(&attsum[nimg * 512 + c + 2], v[2]);
        atomicAdd(&attsum[nimg * 512 + c + 3], v[3]);
      }
    }
    // PV: out = att @ memory_norm; re-read this block's att rows from global
    // (visible: fence + barrier above, same CU).
    const int c0 = tid * 4;
    for (int rr = 0; rr < 16; ++rr) {
      const float* arow = out_att + (size_t)(r0 + rr) * 512;
      f32x4 o = {0.f, 0.f, 0.f, 0.f};
      for (int mm = 0; mm < 512; ++mm) {
        const float a = arow[mm];
        o += a * (*(const f32x4*)(Mnf + (size_t)mm * 1024 + c0));
      }
      *(f32x4*)(out_out + (size_t)(r0 + rr) * 1024 + c0) = o;
    }
  }
}

// ---- att_spatial broadcast: attsum/512 over 32x32 plane ------------------
// grid = 2048 fat blocks (8 planes each), block = 256
__global__ __launch_bounds__(256) void spread(
    const float* __restrict__ attsum, float* __restrict__ out_sp) {
  const int base = blockIdx.x * 8;
  #pragma unroll
  for (int p = 0; p < 8; ++p) {
    const int nm = base + p;
    const float v = attsum[nm] * (1.f / 512.f);
    const f32x4 vv = {v, v, v, v};
    __builtin_nontemporal_store(vv, (f32x4*)(out_sp + (size_t)nm * 1024 + threadIdx.x * 4));
  }
}

// ---- launch --------------------------------------------------------------

extern "C" void kernel_launch(void* const* d_in, const int* in_sizes, int n_in,
                              void* d_out, int out_size, void* d_ws, size_t ws_size,
                              hipStream_t stream) {
  const float* x      = (const float*)d_in[0];  // 32*512*32*32
  const float* memory = (const float*)d_in[1];  // 512*1024
  const float* w1     = (const float*)d_in[2];  // 512*1024
  const float* b1     = (const float*)d_in[3];  // 512
  const float* w2     = (const float*)d_in[4];  // 1024*512
  const float* b2     = (const float*)d_in[5];  // 1024

  float* out = (float*)d_out;
  float* out_output = out;               // 16384*1024
  float* out_attsp  = out + 16777216;    // 32*512*1024
  float* out_flat   = out + 33554432;    // 16384*1024
  float* out_mnorm  = out + 50331648;    // 512*1024
  float* out_att    = out + 50855936;    // 16384*512

  char* ws = (char*)d_ws;
  float*  h      = (float*)ws;                                  // 1 MB (512x512)
  float*  mp     = (float*)(ws + (1 << 20));                    // 2 MB (512x1024)
  __bf16* mnb    = (__bf16*)(ws + (1 << 20) + (2 << 20));       // 1 MB
  float*  attsum = (float*)(ws + (1 << 20) + (2 << 20) + (1 << 20)); // 64 KB

  gemm1<<<dim3(16, 16), 64, 0, stream>>>(memory, w1, b1, h, attsum);
  gemm2<<<dim3(16, 32), 64, 0, stream>>>(h, w2, b2, mp);
  norm_rows<<<512, 256, 0, stream>>>(mp, out_mnorm, mnb);
  attend<<<1024, 256, 0, stream>>>(x, mnb, out_mnorm, out_flat, out_output, out_att, attsum);
  spread<<<2048, 256, 0, stream>>>(attsum, out_attsp);
}

// Round 5
// 424.294 us; speedup vs baseline: 1.0733x; 1.0733x over previous
//
#include <hip/hip_runtime.h>

typedef float  f32x4  __attribute__((ext_vector_type(4)));
typedef __bf16 bf16x8 __attribute__((ext_vector_type(8)));
typedef __bf16 bf16x4 __attribute__((ext_vector_type(4)));

#define L2EPS   1e-12f
#define SHRINKC 0.0025f

// ---- helpers -------------------------------------------------------------

__device__ __forceinline__ bf16x8 pack_bf16(f32x4 v0, f32x4 v1) {
  bf16x8 r;
  r[0] = (__bf16)v0[0]; r[1] = (__bf16)v0[1]; r[2] = (__bf16)v0[2]; r[3] = (__bf16)v0[3];
  r[4] = (__bf16)v1[0]; r[5] = (__bf16)v1[1]; r[6] = (__bf16)v1[2]; r[7] = (__bf16)v1[3];
  return r;
}

__device__ __forceinline__ bf16x8 load_cvt_bf16x8(const float* p) {
  const f32x4* q = (const f32x4*)p;
  return pack_bf16(q[0], q[1]);
}

__device__ __forceinline__ float dot4(f32x4 v) {
  return v[0]*v[0] + v[1]*v[1] + v[2]*v[2] + v[3]*v[3];
}

// ---- copy_flat: out_flat = x (exact fp32 copy), pure streaming ----------
// Runs FIRST: also warms L2/L3 with x before attend reads it.
// grid = 2048, block = 256; 8 f32x4 per thread, grid-stride.
__global__ __launch_bounds__(256) void copy_flat(
    const float* __restrict__ x, float* __restrict__ out_flat) {
  const int stride = 2048 * 256;
  int idx = blockIdx.x * 256 + threadIdx.x;
  #pragma unroll
  for (int i = 0; i < 8; ++i, idx += stride) {
    const f32x4 v = *(const f32x4*)(x + (size_t)idx * 4);
    __builtin_nontemporal_store(v, (f32x4*)(out_flat + (size_t)idx * 4));
  }
}

// ---- gemm1: h = relu(memory @ w1^T + b1), 32x32 tile / 1-wave block ------
// grid = (16,16), block = 64. Also zeroes attsum (64 floats per block).
__global__ __launch_bounds__(64) void gemm1(
    const float* __restrict__ A, const float* __restrict__ B,
    const float* __restrict__ bias, float* __restrict__ C,
    float* __restrict__ attsum) {
  const int bid = blockIdx.y * gridDim.x + blockIdx.x;  // 0..255
  attsum[bid * 64 + threadIdx.x] = 0.f;

  const int K = 1024, N = 512;
  const int r0   = blockIdx.x * 32;
  const int n0   = blockIdx.y * 32;
  const int lane = threadIdx.x & 63;
  const int quad = lane >> 4;
  const int m    = lane & 15;

  f32x4 acc[2][2] = {};
  for (int k0 = 0; k0 < K; k0 += 32) {
    const int kk = k0 + quad * 8;
    bf16x8 a[2], b[2];
    #pragma unroll
    for (int rg = 0; rg < 2; ++rg)
      a[rg] = load_cvt_bf16x8(A + (size_t)(r0 + rg * 16 + m) * K + kk);
    #pragma unroll
    for (int cf = 0; cf < 2; ++cf)
      b[cf] = load_cvt_bf16x8(B + (size_t)(n0 + cf * 16 + m) * K + kk);
    #pragma unroll
    for (int rg = 0; rg < 2; ++rg)
      #pragma unroll
      for (int cf = 0; cf < 2; ++cf)
        acc[rg][cf] = __builtin_amdgcn_mfma_f32_16x16x32_bf16(a[rg], b[cf], acc[rg][cf], 0, 0, 0);
  }
  #pragma unroll
  for (int rg = 0; rg < 2; ++rg)
    #pragma unroll
    for (int cf = 0; cf < 2; ++cf) {
      const int n = n0 + cf * 16 + m;
      const float bv = bias[n];
      #pragma unroll
      for (int vi = 0; vi < 4; ++vi) {
        const int r = r0 + rg * 16 + quad * 4 + vi;
        C[(size_t)r * N + n] = fmaxf(acc[rg][cf][vi] + bv, 0.f);
      }
    }
}

// ---- gemm2: mp = relu(h @ w2^T + b2), 32x32 tile / 1-wave block ----------
// grid = (16, 32), block = 64. 512 blocks: 2 blocks/CU, latency hidden.
// (Round-2 lesson: a 16-block fused variant ran at 150 us, 0.7% occupancy.)
__global__ __launch_bounds__(64) void gemm2(
    const float* __restrict__ A, const float* __restrict__ B,
    const float* __restrict__ bias, float* __restrict__ C) {
  const int K = 512, N = 1024;
  const int r0   = blockIdx.x * 32;
  const int n0   = blockIdx.y * 32;
  const int lane = threadIdx.x & 63;
  const int quad = lane >> 4;
  const int m    = lane & 15;

  f32x4 acc[2][2] = {};
  for (int k0 = 0; k0 < K; k0 += 32) {
    const int kk = k0 + quad * 8;
    bf16x8 a[2], b[2];
    #pragma unroll
    for (int rg = 0; rg < 2; ++rg)
      a[rg] = load_cvt_bf16x8(A + (size_t)(r0 + rg * 16 + m) * K + kk);
    #pragma unroll
    for (int cf = 0; cf < 2; ++cf)
      b[cf] = load_cvt_bf16x8(B + (size_t)(n0 + cf * 16 + m) * K + kk);
    #pragma unroll
    for (int rg = 0; rg < 2; ++rg)
      #pragma unroll
      for (int cf = 0; cf < 2; ++cf)
        acc[rg][cf] = __builtin_amdgcn_mfma_f32_16x16x32_bf16(a[rg], b[cf], acc[rg][cf], 0, 0, 0);
  }
  #pragma unroll
  for (int rg = 0; rg < 2; ++rg)
    #pragma unroll
    for (int cf = 0; cf < 2; ++cf) {
      const int n = n0 + cf * 16 + m;
      const float bv = bias[n];
      #pragma unroll
      for (int vi = 0; vi < 4; ++vi) {
        const int r = r0 + rg * 16 + quad * 4 + vi;
        C[(size_t)r * N + n] = fmaxf(acc[rg][cf][vi] + bv, 0.f);
      }
    }
}

// ---- normalize mem_proc rows -> memory_norm (fp32 out + bf16 ws copy) ----
// grid = 512, block = 256
__global__ __launch_bounds__(256) void norm_rows(
    const float* __restrict__ mp, float* __restrict__ mn_f32,
    __bf16* __restrict__ mn_bf16) {
  const int r = blockIdx.x;
  const int tid = threadIdx.x;
  const f32x4 v = *(const f32x4*)(mp + (size_t)r * 1024 + tid * 4);
  float ss = dot4(v);
  #pragma unroll
  for (int d = 1; d < 64; d <<= 1) ss += __shfl_xor(ss, d);
  __shared__ float wsum[4];
  __shared__ float invs;
  if ((tid & 63) == 0) wsum[tid >> 6] = ss;
  __syncthreads();
  if (tid == 0) {
    float t = wsum[0] + wsum[1] + wsum[2] + wsum[3];
    invs = 1.f / fmaxf(sqrtf(t), L2EPS);
  }
  __syncthreads();
  const float iv = invs;
  f32x4 o = v * iv;
  *(f32x4*)(mn_f32 + (size_t)r * 1024 + tid * 4) = o;
  bf16x4 ob;
  ob[0] = (__bf16)o[0]; ob[1] = (__bf16)o[1]; ob[2] = (__bf16)o[2]; ob[3] = (__bf16)o[3];
  *(bf16x4*)(mn_bf16 + (size_t)r * 1024 + tid * 4) = ob;
}

// ---- fused attention, register-resident softmax, 32 rows/block -----------
// Swapped MFMA operands: mfma(A=Mn rows, B=x rows) puts, in each lane,
// 32 score values (8 nf-tiles x 4 vi) belonging to ONE x-row:
//   row = rg*16 + (lane&15), col = n0w + nf*16 + (lane>>4)*4 + vi
// Softmax is in-register: shfl_xor(16|32) over quads + 1 KB LDS cross-wave.
// grid = 512 (32 rows each), block = 256 (4 waves; wave w owns cols w*128..)
// Round-4 lessons applied: NO stores inside the K-loop (loads and stores
// share vmcnt; in-loop NT stores serialized every wave on store retirement),
// and 32 rows/block (16-row variant doubled per-block Mn traffic: 190 us).
// Explicit 1-deep x prefetch keeps next iter's loads in flight under MFMA.
__global__ __launch_bounds__(256) void attend(
    const float* __restrict__ x, const __bf16* __restrict__ Mn,
    const float* __restrict__ Mnf, float* __restrict__ out_out,
    float* __restrict__ out_att, float* __restrict__ attsum) {
  __shared__ float red[2][4][32];  // [phase][wave][row] partial sums, 1 KB
  const int r0   = blockIdx.x * 32;
  const int tid  = threadIdx.x;
  const int wave = tid >> 6;
  const int lane = tid & 63;
  const int quad = lane >> 4;
  const int m    = lane & 15;
  const int n0w  = wave * 128;

  const float* xr0 = x + (size_t)(r0 + m) * 1024;
  const float* xr1 = x + (size_t)(r0 + 16 + m) * 1024;

  float ss0 = 0.f, ss1 = 0.f;
  f32x4 acc[8][2] = {};
  // prologue: load iter-0 x
  f32x4 c0a, c0b, c1a, c1b;
  {
    const int kk = quad * 8;
    const f32x4* q0 = (const f32x4*)(xr0 + kk);
    const f32x4* q1 = (const f32x4*)(xr1 + kk);
    c0a = q0[0]; c0b = q0[1];
    c1a = q1[0]; c1b = q1[1];
  }
  for (int k0 = 0; k0 < 1024; k0 += 32) {
    const int kk = k0 + quad * 8;
    // issue next iter's x loads first (in flight under this iter's MFMA)
    f32x4 n0a, n0b, n1a, n1b;
    if (k0 + 32 < 1024) {
      const f32x4* q0 = (const f32x4*)(xr0 + kk + 32);
      const f32x4* q1 = (const f32x4*)(xr1 + kk + 32);
      n0a = q0[0]; n0b = q0[1];
      n1a = q1[0]; n1b = q1[1];
    }
    bf16x8 b0 = pack_bf16(c0a, c0b);
    bf16x8 b1 = pack_bf16(c1a, c1b);
    ss0 += dot4(c0a) + dot4(c0b);
    ss1 += dot4(c1a) + dot4(c1b);
    #pragma unroll
    for (int nf = 0; nf < 8; ++nf) {
      const bf16x8 a = *(const bf16x8*)(Mn + (size_t)(n0w + nf * 16 + m) * 1024 + kk);
      acc[nf][0] = __builtin_amdgcn_mfma_f32_16x16x32_bf16(a, b0, acc[nf][0], 0, 0, 0);
      acc[nf][1] = __builtin_amdgcn_mfma_f32_16x16x32_bf16(a, b1, acc[nf][1], 0, 0, 0);
    }
    c0a = n0a; c0b = n0b; c1a = n1a; c1b = n1b;
  }
  // row sumsq: reduce across quads (lanes share m) -> every lane has both rows
  ss0 += __shfl_xor(ss0, 16); ss0 += __shfl_xor(ss0, 32);
  ss1 += __shfl_xor(ss1, 16); ss1 += __shfl_xor(ss1, 32);
  const float iv0 = 1.f / fmaxf(sqrtf(ss0), L2EPS);
  const float iv1 = 1.f / fmaxf(sqrtf(ss1), L2EPS);

  // exp in place (no max-shift: scores are cosines in [-1,1]), per-row sums
  float se0 = 0.f, se1 = 0.f;
  #pragma unroll
  for (int nf = 0; nf < 8; ++nf)
    #pragma unroll
    for (int vi = 0; vi < 4; ++vi) {
      const float e0 = __expf(acc[nf][0][vi] * iv0);
      const float e1 = __expf(acc[nf][1][vi] * iv1);
      acc[nf][0][vi] = e0; acc[nf][1][vi] = e1;
      se0 += e0; se1 += e1;
    }
  se0 += __shfl_xor(se0, 16); se0 += __shfl_xor(se0, 32);
  se1 += __shfl_xor(se1, 16); se1 += __shfl_xor(se1, 32);
  if (quad == 0) { red[0][wave][m] = se0; red[0][wave][16 + m] = se1; }
  __syncthreads();
  const float te0 = red[0][0][m] + red[0][1][m] + red[0][2][m] + red[0][3][m];
  const float te1 = red[0][0][16 + m] + red[0][1][16 + m] + red[0][2][16 + m] + red[0][3][16 + m];
  const float ie0 = 1.f / te0;
  const float ie1 = 1.f / te1;

  // shrink in place, accumulate row sums of surviving mass
  float rs0 = 0.f, rs1 = 0.f;
  #pragma unroll
  for (int nf = 0; nf < 8; ++nf)
    #pragma unroll
    for (int vi = 0; vi < 4; ++vi) {
      const float s0 = fmaxf(acc[nf][0][vi] * ie0 - SHRINKC, 0.f);
      const float s1 = fmaxf(acc[nf][1][vi] * ie1 - SHRINKC, 0.f);
      acc[nf][0][vi] = s0; acc[nf][1][vi] = s1;
      rs0 += s0; rs1 += s1;
    }
  rs0 += __shfl_xor(rs0, 16); rs0 += __shfl_xor(rs0, 32);
  rs1 += __shfl_xor(rs1, 16); rs1 += __shfl_xor(rs1, 32);
  if (quad == 0) { red[1][wave][m] = rs0; red[1][wave][16 + m] = rs1; }
  __syncthreads();
  const float tr0 = red[1][0][m] + red[1][1][m] + red[1][2][m] + red[1][3][m];
  const float tr1 = red[1][0][16 + m] + red[1][1][16 + m] + red[1][2][16 + m] + red[1][3][16 + m];
  const float ir0 = 1.f / fmaxf(tr0, L2EPS);
  const float ir1 = 1.f / fmaxf(tr1, L2EPS);

  // final att values straight from registers (f32x4, line-coalesced)
  #pragma unroll
  for (int nf = 0; nf < 8; ++nf) {
    acc[nf][0] *= ir0;
    acc[nf][1] *= ir1;
    __builtin_nontemporal_store(acc[nf][0],
        (f32x4*)(out_att + (size_t)(r0 + m)      * 512 + n0w + nf * 16 + quad * 4));
    __builtin_nontemporal_store(acc[nf][1],
        (f32x4*)(out_att + (size_t)(r0 + 16 + m) * 512 + n0w + nf * 16 + quad * 4));
  }
  __threadfence_block();
  const int any = __syncthreads_or(tr0 + tr1 > 0.f);

  if (!any) {
    // fast path (data-driven): all rows shrunk to zero -> output rows are 0,
    // attsum contribution is 0. Pure streaming store.
    const f32x4 z = {0.f, 0.f, 0.f, 0.f};
    float* dst = out_out + (size_t)r0 * 1024;
    for (int idx = tid; idx < 32 * 1024 / 4; idx += 256)
      __builtin_nontemporal_store(z, (f32x4*)(dst + idx * 4));
  } else {
    // general path (correctness-only; not taken on this data distribution)
    const int nimg = r0 >> 9;
    #pragma unroll
    for (int nf = 0; nf < 8; ++nf) {
      f32x4 v = acc[nf][0] + acc[nf][1];  // sum the lane's two rows (same col)
      #pragma unroll
      for (int d = 1; d < 16; d <<= 1) {
        v[0] += __shfl_xor(v[0], d); v[1] += __shfl_xor(v[1], d);
        v[2] += __shfl_xor(v[2], d); v[3] += __shfl_xor(v[3], d);
      }
      if (m == 0) {
        const int c = n0w + nf * 16 + quad * 4;
        atomicAdd(&attsum[nimg * 512 + c + 0], v[0]);
        atomicAdd(&attsum[nimg * 512 + c + 1], v[1]);
        atomicAdd(&attsum[nimg * 512 + c + 2], v[2]);
        atomicAdd(&attsum[nimg * 512 + c + 3], v[3]);
      }
    }
    // PV: out = att @ memory_norm; re-read this block's att rows from global
    // (visible: fence + barrier above, same CU).
    const int c0 = tid * 4;
    for (int rr = 0; rr < 32; ++rr) {
      const float* arow = out_att + (size_t)(r0 + rr) * 512;
      f32x4 o = {0.f, 0.f, 0.f, 0.f};
      for (int mm = 0; mm < 512; ++mm) {
        const float a = arow[mm];
        o += a * (*(const f32x4*)(Mnf + (size_t)mm * 1024 + c0));
      }
      *(f32x4*)(out_out + (size_t)(r0 + rr) * 1024 + c0) = o;
    }
  }
}

// ---- att_spatial broadcast: attsum/512 over 32x32 plane ------------------
// grid = 2048 fat blocks (8 planes each), block = 256
__global__ __launch_bounds__(256) void spread(
    const float* __restrict__ attsum, float* __restrict__ out_sp) {
  const int base = blockIdx.x * 8;
  #pragma unroll
  for (int p = 0; p < 8; ++p) {
    const int nm = base + p;
    const float v = attsum[nm] * (1.f / 512.f);
    const f32x4 vv = {v, v, v, v};
    __builtin_nontemporal_store(vv, (f32x4*)(out_sp + (size_t)nm * 1024 + threadIdx.x * 4));
  }
}

// ---- launch --------------------------------------------------------------

extern "C" void kernel_launch(void* const* d_in, const int* in_sizes, int n_in,
                              void* d_out, int out_size, void* d_ws, size_t ws_size,
                              hipStream_t stream) {
  const float* x      = (const float*)d_in[0];  // 32*512*32*32
  const float* memory = (const float*)d_in[1];  // 512*1024
  const float* w1     = (const float*)d_in[2];  // 512*1024
  const float* b1     = (const float*)d_in[3];  // 512
  const float* w2     = (const float*)d_in[4];  // 1024*512
  const float* b2     = (const float*)d_in[5];  // 1024

  float* out = (float*)d_out;
  float* out_output = out;               // 16384*1024
  float* out_attsp  = out + 16777216;    // 32*512*1024
  float* out_flat   = out + 33554432;    // 16384*1024
  float* out_mnorm  = out + 50331648;    // 512*1024
  float* out_att    = out + 50855936;    // 16384*512

  char* ws = (char*)d_ws;
  float*  h      = (float*)ws;                                  // 1 MB (512x512)
  float*  mp     = (float*)(ws + (1 << 20));                    // 2 MB (512x1024)
  __bf16* mnb    = (__bf16*)(ws + (1 << 20) + (2 << 20));       // 1 MB
  float*  attsum = (float*)(ws + (1 << 20) + (2 << 20) + (1 << 20)); // 64 KB

  copy_flat<<<2048, 256, 0, stream>>>(x, out_flat);
  gemm1<<<dim3(16, 16), 64, 0, stream>>>(memory, w1, b1, h, attsum);
  gemm2<<<dim3(16, 32), 64, 0, stream>>>(h, w2, b2, mp);
  norm_rows<<<512, 256, 0, stream>>>(mp, out_mnorm, mnb);
  attend<<<512, 256, 0, stream>>>(x, mnb, out_mnorm, out_output, out_att, attsum);
  spread<<<2048, 256, 0, stream>>>(attsum, out_attsp);
}

// Round 6
// 399.363 us; speedup vs baseline: 1.1403x; 1.0624x over previous
//
#include <hip/hip_runtime.h>

typedef float  f32x4  __attribute__((ext_vector_type(4)));
typedef __bf16 bf16x8 __attribute__((ext_vector_type(8)));
typedef __bf16 bf16x4 __attribute__((ext_vector_type(4)));

#define L2EPS   1e-12f
#define SHRINKC 0.0025f

// ---- helpers -------------------------------------------------------------

__device__ __forceinline__ bf16x8 pack_bf16(f32x4 v0, f32x4 v1) {
  bf16x8 r;
  r[0] = (__bf16)v0[0]; r[1] = (__bf16)v0[1]; r[2] = (__bf16)v0[2]; r[3] = (__bf16)v0[3];
  r[4] = (__bf16)v1[0]; r[5] = (__bf16)v1[1]; r[6] = (__bf16)v1[2]; r[7] = (__bf16)v1[3];
  return r;
}

__device__ __forceinline__ bf16x8 load_cvt_bf16x8(const float* p) {
  const f32x4* q = (const f32x4*)p;
  return pack_bf16(q[0], q[1]);
}

__device__ __forceinline__ float dot4(f32x4 v) {
  return v[0]*v[0] + v[1]*v[1] + v[2]*v[2] + v[3]*v[3];
}

// ---- gemm1: h = relu(memory @ w1^T + b1), 32x32 tile / 1-wave block ------
// grid = (16,16), block = 64. Also zeroes attsum (64 floats per block).
__global__ __launch_bounds__(64) void gemm1(
    const float* __restrict__ A, const float* __restrict__ B,
    const float* __restrict__ bias, float* __restrict__ C,
    float* __restrict__ attsum) {
  const int bid = blockIdx.y * gridDim.x + blockIdx.x;  // 0..255
  attsum[bid * 64 + threadIdx.x] = 0.f;

  const int K = 1024, N = 512;
  const int r0   = blockIdx.x * 32;
  const int n0   = blockIdx.y * 32;
  const int lane = threadIdx.x & 63;
  const int quad = lane >> 4;
  const int m    = lane & 15;

  f32x4 acc[2][2] = {};
  for (int k0 = 0; k0 < K; k0 += 32) {
    const int kk = k0 + quad * 8;
    bf16x8 a[2], b[2];
    #pragma unroll
    for (int rg = 0; rg < 2; ++rg)
      a[rg] = load_cvt_bf16x8(A + (size_t)(r0 + rg * 16 + m) * K + kk);
    #pragma unroll
    for (int cf = 0; cf < 2; ++cf)
      b[cf] = load_cvt_bf16x8(B + (size_t)(n0 + cf * 16 + m) * K + kk);
    #pragma unroll
    for (int rg = 0; rg < 2; ++rg)
      #pragma unroll
      for (int cf = 0; cf < 2; ++cf)
        acc[rg][cf] = __builtin_amdgcn_mfma_f32_16x16x32_bf16(a[rg], b[cf], acc[rg][cf], 0, 0, 0);
  }
  #pragma unroll
  for (int rg = 0; rg < 2; ++rg)
    #pragma unroll
    for (int cf = 0; cf < 2; ++cf) {
      const int n = n0 + cf * 16 + m;
      const float bv = bias[n];
      #pragma unroll
      for (int vi = 0; vi < 4; ++vi) {
        const int r = r0 + rg * 16 + quad * 4 + vi;
        C[(size_t)r * N + n] = fmaxf(acc[rg][cf][vi] + bv, 0.f);
      }
    }
}

// ---- gemm2: mp = relu(h @ w2^T + b2), 32x32 tile / 1-wave block ----------
// grid = (16, 32), block = 64. 512 blocks: 2 blocks/CU, latency hidden.
// (Round-2 lesson: a 16-block fused variant ran at 150 us, 0.7% occupancy.)
__global__ __launch_bounds__(64) void gemm2(
    const float* __restrict__ A, const float* __restrict__ B,
    const float* __restrict__ bias, float* __restrict__ C) {
  const int K = 512, N = 1024;
  const int r0   = blockIdx.x * 32;
  const int n0   = blockIdx.y * 32;
  const int lane = threadIdx.x & 63;
  const int quad = lane >> 4;
  const int m    = lane & 15;

  f32x4 acc[2][2] = {};
  for (int k0 = 0; k0 < K; k0 += 32) {
    const int kk = k0 + quad * 8;
    bf16x8 a[2], b[2];
    #pragma unroll
    for (int rg = 0; rg < 2; ++rg)
      a[rg] = load_cvt_bf16x8(A + (size_t)(r0 + rg * 16 + m) * K + kk);
    #pragma unroll
    for (int cf = 0; cf < 2; ++cf)
      b[cf] = load_cvt_bf16x8(B + (size_t)(n0 + cf * 16 + m) * K + kk);
    #pragma unroll
    for (int rg = 0; rg < 2; ++rg)
      #pragma unroll
      for (int cf = 0; cf < 2; ++cf)
        acc[rg][cf] = __builtin_amdgcn_mfma_f32_16x16x32_bf16(a[rg], b[cf], acc[rg][cf], 0, 0, 0);
  }
  #pragma unroll
  for (int rg = 0; rg < 2; ++rg)
    #pragma unroll
    for (int cf = 0; cf < 2; ++cf) {
      const int n = n0 + cf * 16 + m;
      const float bv = bias[n];
      #pragma unroll
      for (int vi = 0; vi < 4; ++vi) {
        const int r = r0 + rg * 16 + quad * 4 + vi;
        C[(size_t)r * N + n] = fmaxf(acc[rg][cf][vi] + bv, 0.f);
      }
    }
}

// ---- normalize mem_proc rows -> memory_norm (fp32 out + bf16 ws copy) ----
// grid = 512, block = 256
__global__ __launch_bounds__(256) void norm_rows(
    const float* __restrict__ mp, float* __restrict__ mn_f32,
    __bf16* __restrict__ mn_bf16) {
  const int r = blockIdx.x;
  const int tid = threadIdx.x;
  const f32x4 v = *(const f32x4*)(mp + (size_t)r * 1024 + tid * 4);
  float ss = dot4(v);
  #pragma unroll
  for (int d = 1; d < 64; d <<= 1) ss += __shfl_xor(ss, d);
  __shared__ float wsum[4];
  __shared__ float invs;
  if ((tid & 63) == 0) wsum[tid >> 6] = ss;
  __syncthreads();
  if (tid == 0) {
    float t = wsum[0] + wsum[1] + wsum[2] + wsum[3];
    invs = 1.f / fmaxf(sqrtf(t), L2EPS);
  }
  __syncthreads();
  const float iv = invs;
  f32x4 o = v * iv;
  *(f32x4*)(mn_f32 + (size_t)r * 1024 + tid * 4) = o;
  bf16x4 ob;
  ob[0] = (__bf16)o[0]; ob[1] = (__bf16)o[1]; ob[2] = (__bf16)o[2]; ob[3] = (__bf16)o[3];
  *(bf16x4*)(mn_bf16 + (size_t)r * 1024 + tid * 4) = ob;
}

// ---- fused attention, register-resident softmax, 32 rows/block -----------
// Round-3 structure (best measured: 404 us total) + round-5's 1-deep x
// prefetch (the only round-5 piece that helped). Flat copy of x stays IN
// the K-loop (round-5 falsified the "in-loop NT stores serialize" theory:
// removing them saved <=5 us while a separate copy kernel cost 21 us).
// Swapped MFMA operands: mfma(A=Mn rows, B=x rows) puts, in each lane,
// 32 score values (8 nf-tiles x 4 vi) belonging to ONE x-row:
//   row = rg*16 + (lane&15), col = n0w + nf*16 + (lane>>4)*4 + vi
// grid = 512 (32 rows each), block = 256 (4 waves; wave w owns cols w*128..)
// flat-copy distributed: wave w writes k-range [256w, 256w+256).
__global__ __launch_bounds__(256) void attend(
    const float* __restrict__ x, const __bf16* __restrict__ Mn,
    const float* __restrict__ Mnf, float* __restrict__ out_flat,
    float* __restrict__ out_out, float* __restrict__ out_att,
    float* __restrict__ attsum) {
  __shared__ float red[2][4][32];  // [phase][wave][row] partial sums, 1 KB
  const int r0   = blockIdx.x * 32;
  const int tid  = threadIdx.x;
  const int wave = tid >> 6;
  const int lane = tid & 63;
  const int quad = lane >> 4;
  const int m    = lane & 15;
  const int n0w  = wave * 128;

  const float* xr0 = x + (size_t)(r0 + m) * 1024;
  const float* xr1 = x + (size_t)(r0 + 16 + m) * 1024;

  float ss0 = 0.f, ss1 = 0.f;
  f32x4 acc[8][2] = {};
  // prologue: load iter-0 x
  f32x4 c0a, c0b, c1a, c1b;
  {
    const int kk = quad * 8;
    const f32x4* q0 = (const f32x4*)(xr0 + kk);
    const f32x4* q1 = (const f32x4*)(xr1 + kk);
    c0a = q0[0]; c0b = q0[1];
    c1a = q1[0]; c1b = q1[1];
  }
  for (int k0 = 0; k0 < 1024; k0 += 32) {
    const int kk = k0 + quad * 8;
    // issue next iter's x loads first (in flight under this iter's MFMA)
    f32x4 n0a, n0b, n1a, n1b;
    if (k0 + 32 < 1024) {
      const f32x4* q0 = (const f32x4*)(xr0 + kk + 32);
      const f32x4* q1 = (const f32x4*)(xr1 + kk + 32);
      n0a = q0[0]; n0b = q0[1];
      n1a = q1[0]; n1b = q1[1];
    }
    if ((k0 >> 8) == wave) {
      // exact fp32 copy of x -> input_flat, spread over the 4 waves
      float* d0 = out_flat + (size_t)(r0 + m) * 1024 + kk;
      float* d1 = out_flat + (size_t)(r0 + 16 + m) * 1024 + kk;
      __builtin_nontemporal_store(c0a, (f32x4*)d0);
      __builtin_nontemporal_store(c0b, (f32x4*)(d0 + 4));
      __builtin_nontemporal_store(c1a, (f32x4*)d1);
      __builtin_nontemporal_store(c1b, (f32x4*)(d1 + 4));
    }
    bf16x8 b0 = pack_bf16(c0a, c0b);
    bf16x8 b1 = pack_bf16(c1a, c1b);
    ss0 += dot4(c0a) + dot4(c0b);
    ss1 += dot4(c1a) + dot4(c1b);
    #pragma unroll
    for (int nf = 0; nf < 8; ++nf) {
      const bf16x8 a = *(const bf16x8*)(Mn + (size_t)(n0w + nf * 16 + m) * 1024 + kk);
      acc[nf][0] = __builtin_amdgcn_mfma_f32_16x16x32_bf16(a, b0, acc[nf][0], 0, 0, 0);
      acc[nf][1] = __builtin_amdgcn_mfma_f32_16x16x32_bf16(a, b1, acc[nf][1], 0, 0, 0);
    }
    c0a = n0a; c0b = n0b; c1a = n1a; c1b = n1b;
  }
  // row sumsq: reduce across quads (lanes share m) -> every lane has both rows
  ss0 += __shfl_xor(ss0, 16); ss0 += __shfl_xor(ss0, 32);
  ss1 += __shfl_xor(ss1, 16); ss1 += __shfl_xor(ss1, 32);
  const float iv0 = 1.f / fmaxf(sqrtf(ss0), L2EPS);
  const float iv1 = 1.f / fmaxf(sqrtf(ss1), L2EPS);

  // exp in place (no max-shift: scores are cosines in [-1,1]), per-row sums
  float se0 = 0.f, se1 = 0.f;
  #pragma unroll
  for (int nf = 0; nf < 8; ++nf)
    #pragma unroll
    for (int vi = 0; vi < 4; ++vi) {
      const float e0 = __expf(acc[nf][0][vi] * iv0);
      const float e1 = __expf(acc[nf][1][vi] * iv1);
      acc[nf][0][vi] = e0; acc[nf][1][vi] = e1;
      se0 += e0; se1 += e1;
    }
  se0 += __shfl_xor(se0, 16); se0 += __shfl_xor(se0, 32);
  se1 += __shfl_xor(se1, 16); se1 += __shfl_xor(se1, 32);
  if (quad == 0) { red[0][wave][m] = se0; red[0][wave][16 + m] = se1; }
  __syncthreads();
  const float te0 = red[0][0][m] + red[0][1][m] + red[0][2][m] + red[0][3][m];
  const float te1 = red[0][0][16 + m] + red[0][1][16 + m] + red[0][2][16 + m] + red[0][3][16 + m];
  const float ie0 = 1.f / te0;
  const float ie1 = 1.f / te1;

  // shrink in place, accumulate row sums of surviving mass
  float rs0 = 0.f, rs1 = 0.f;
  #pragma unroll
  for (int nf = 0; nf < 8; ++nf)
    #pragma unroll
    for (int vi = 0; vi < 4; ++vi) {
      const float s0 = fmaxf(acc[nf][0][vi] * ie0 - SHRINKC, 0.f);
      const float s1 = fmaxf(acc[nf][1][vi] * ie1 - SHRINKC, 0.f);
      acc[nf][0][vi] = s0; acc[nf][1][vi] = s1;
      rs0 += s0; rs1 += s1;
    }
  rs0 += __shfl_xor(rs0, 16); rs0 += __shfl_xor(rs0, 32);
  rs1 += __shfl_xor(rs1, 16); rs1 += __shfl_xor(rs1, 32);
  if (quad == 0) { red[1][wave][m] = rs0; red[1][wave][16 + m] = rs1; }
  __syncthreads();
  const float tr0 = red[1][0][m] + red[1][1][m] + red[1][2][m] + red[1][3][m];
  const float tr1 = red[1][0][16 + m] + red[1][1][16 + m] + red[1][2][16 + m] + red[1][3][16 + m];
  const float ir0 = 1.f / fmaxf(tr0, L2EPS);
  const float ir1 = 1.f / fmaxf(tr1, L2EPS);

  // final att values straight from registers (f32x4, line-coalesced)
  #pragma unroll
  for (int nf = 0; nf < 8; ++nf) {
    acc[nf][0] *= ir0;
    acc[nf][1] *= ir1;
    __builtin_nontemporal_store(acc[nf][0],
        (f32x4*)(out_att + (size_t)(r0 + m)      * 512 + n0w + nf * 16 + quad * 4));
    __builtin_nontemporal_store(acc[nf][1],
        (f32x4*)(out_att + (size_t)(r0 + 16 + m) * 512 + n0w + nf * 16 + quad * 4));
  }
  __threadfence_block();
  const int any = __syncthreads_or(tr0 + tr1 > 0.f);

  if (!any) {
    // fast path (data-driven): all rows shrunk to zero -> output rows are 0,
    // attsum contribution is 0. Pure streaming store.
    const f32x4 z = {0.f, 0.f, 0.f, 0.f};
    float* dst = out_out + (size_t)r0 * 1024;
    for (int idx = tid; idx < 32 * 1024 / 4; idx += 256)
      __builtin_nontemporal_store(z, (f32x4*)(dst + idx * 4));
  } else {
    // general path (correctness-only; not taken on this data distribution)
    const int nimg = r0 >> 9;
    #pragma unroll
    for (int nf = 0; nf < 8; ++nf) {
      f32x4 v = acc[nf][0] + acc[nf][1];  // sum the lane's two rows (same col)
      #pragma unroll
      for (int d = 1; d < 16; d <<= 1) {
        v[0] += __shfl_xor(v[0], d); v[1] += __shfl_xor(v[1], d);
        v[2] += __shfl_xor(v[2], d); v[3] += __shfl_xor(v[3], d);
      }
      if (m == 0) {
        const int c = n0w + nf * 16 + quad * 4;
        atomicAdd(&attsum[nimg * 512 + c + 0], v[0]);
        atomicAdd(&attsum[nimg * 512 + c + 1], v[1]);
        atomicAdd(&attsum[nimg * 512 + c + 2], v[2]);
        atomicAdd(&attsum[nimg * 512 + c + 3], v[3]);
      }
    }
    // PV: out = att @ memory_norm; re-read this block's att rows from global
    // (visible: fence + barrier above, same CU).
    const int c0 = tid * 4;
    for (int rr = 0; rr < 32; ++rr) {
      const float* arow = out_att + (size_t)(r0 + rr) * 512;
      f32x4 o = {0.f, 0.f, 0.f, 0.f};
      for (int mm = 0; mm < 512; ++mm) {
        const float a = arow[mm];
        o += a * (*(const f32x4*)(Mnf + (size_t)mm * 1024 + c0));
      }
      *(f32x4*)(out_out + (size_t)(r0 + rr) * 1024 + c0) = o;
    }
  }
}

// ---- att_spatial broadcast: attsum/512 over 32x32 plane ------------------
// grid = 2048 fat blocks (8 planes each), block = 256
__global__ __launch_bounds__(256) void spread(
    const float* __restrict__ attsum, float* __restrict__ out_sp) {
  const int base = blockIdx.x * 8;
  #pragma unroll
  for (int p = 0; p < 8; ++p) {
    const int nm = base + p;
    const float v = attsum[nm] * (1.f / 512.f);
    const f32x4 vv = {v, v, v, v};
    __builtin_nontemporal_store(vv, (f32x4*)(out_sp + (size_t)nm * 1024 + threadIdx.x * 4));
  }
}

// ---- launch --------------------------------------------------------------

extern "C" void kernel_launch(void* const* d_in, const int* in_sizes, int n_in,
                              void* d_out, int out_size, void* d_ws, size_t ws_size,
                              hipStream_t stream) {
  const float* x      = (const float*)d_in[0];  // 32*512*32*32
  const float* memory = (const float*)d_in[1];  // 512*1024
  const float* w1     = (const float*)d_in[2];  // 512*1024
  const float* b1     = (const float*)d_in[3];  // 512
  const float* w2     = (const float*)d_in[4];  // 1024*512
  const float* b2     = (const float*)d_in[5];  // 1024

  float* out = (float*)d_out;
  float* out_output = out;               // 16384*1024
  float* out_attsp  = out + 16777216;    // 32*512*1024
  float* out_flat   = out + 33554432;    // 16384*1024
  float* out_mnorm  = out + 50331648;    // 512*1024
  float* out_att    = out + 50855936;    // 16384*512

  char* ws = (char*)d_ws;
  float*  h      = (float*)ws;                                  // 1 MB (512x512)
  float*  mp     = (float*)(ws + (1 << 20));                    // 2 MB (512x1024)
  __bf16* mnb    = (__bf16*)(ws + (1 << 20) + (2 << 20));       // 1 MB
  float*  attsum = (float*)(ws + (1 << 20) + (2 << 20) + (1 << 20)); // 64 KB

  gemm1<<<dim3(16, 16), 64, 0, stream>>>(memory, w1, b1, h, attsum);
  gemm2<<<dim3(16, 32), 64, 0, stream>>>(h, w2, b2, mp);
  norm_rows<<<512, 256, 0, stream>>>(mp, out_mnorm, mnb);
  attend<<<512, 256, 0, stream>>>(x, mnb, out_mnorm, out_flat, out_output, out_att, attsum);
  spread<<<2048, 256, 0, stream>>>(attsum, out_attsp);
}